// Round 10
// baseline (1272.288 us; speedup 1.0000x reference)
//
#include <hip/hip_runtime.h>
#include <hip/hip_bf16.h>

// CognitiveWorkspace — DIAGNOSTIC round: amplified kernels so each dispatch
// exceeds the harness-fill 265µs rocprof top-5 cutoff and reports counters.
//   K_copy : full S->out copy, repeated 2x inside one dispatch
//   K_gate : gate compute (bf16 MFMA) + hub epilogue, repeated 4x
//   K_fixup: spoke/hub_priv/tag overwrite (single)
// All reps idempotent -> identical output every call; asm memory clobbers
// prevent load-CSE across reps. True cost = dispatch dur / reps.

#define DM 2048      // d_model
#define DSZ 6656     // D_S
#define HUBOFF 4608  // hub_shared offset (floats)
#define TAGOFF 5120
#define NTOK 16384   // B*T
#define DHS 512      // d_hub_shared

typedef __attribute__((ext_vector_type(8))) short bf16x8;
typedef __attribute__((ext_vector_type(4))) float f32x4;

__device__ __forceinline__ float sigmoidf_(float x) {
  return 1.0f / (1.0f + __expf(-x));
}
__device__ __forceinline__ short f2bf(float x) {
  return (short)__bfloat16_as_ushort(__float2bfloat16(x));
}
__device__ __forceinline__ bf16x8 load_bf8(const float* p) {
  float4 a = *reinterpret_cast<const float4*>(p);
  float4 b = *reinterpret_cast<const float4*>(p + 4);
  bf16x8 r;
  r[0] = f2bf(a.x); r[1] = f2bf(a.y); r[2] = f2bf(a.z); r[3] = f2bf(a.w);
  r[4] = f2bf(b.x); r[5] = f2bf(b.y); r[6] = f2bf(b.z); r[7] = f2bf(b.w);
  return r;
}

// ---------------------------------------------------------------------------
// K_copy: flat float4 copy S -> outS, whole pass repeated 2x in-dispatch.
// ---------------------------------------------------------------------------
__global__ __launch_bounds__(256) void cw_copy_kernel(
    const float4* __restrict__ S4, float4* __restrict__ O4)
{
  const size_t base = (size_t)blockIdx.x * 256 + threadIdx.x;
  const size_t stride = (size_t)4096 * 256;
  for (int rep = 0; rep < 2; ++rep) {
    size_t i = base;
#pragma unroll 2
    for (int k = 0; k < 26; ++k) {
      O4[i] = S4[i];
      i += stride;
    }
    asm volatile("" ::: "memory");   // block load-CSE across reps
  }
}

// ---------------------------------------------------------------------------
// K_gate: 1024 blocks, 16 tokens each; full phase chain repeated 4x.
// MFMA 16x16x32 bf16 (m89-verified layouts).
// ---------------------------------------------------------------------------
__global__ __launch_bounds__(256) void cw_gate_kernel(
    const float* __restrict__ S, const float* __restrict__ H,
    const float* __restrict__ Wq, const float* __restrict__ Wg,
    const float* __restrict__ bg, const float* __restrict__ whs,
    const int* __restrict__ lip,
    float* __restrict__ outS, float* __restrict__ gate_out)
{
  __shared__ float gin[16][132];

  const int tid = threadIdx.x;
  const int li = *lip;
  const int start = (li > 8) ? (li - 8) : 0;
  const int ntags = li - start;
  const float tscale = (ntags > 0) ? (1.0f / (float)ntags) : 0.0f;
  const int trs = TAGOFF + start * 64;
  const int tok0 = blockIdx.x * 16;

  const int w = tid >> 6;
  const int l = tid & 63;
  const int l15 = l & 15, l4 = l >> 4;

  for (int rep = 0; rep < 4; ++rep) {
    __syncthreads();   // protect gin against previous rep's readers

    // ---- ph1: mean over past tags
#pragma unroll
    for (int r = 0; r < 4; ++r) {
      int o = r * 256 + tid;        // 16 tok x 64 d
      int tk = o >> 6, d = o & 63;
      const float* sp = S + (size_t)(tok0 + tk) * DSZ + trs + d;
      float acc = 0.f;
      for (int g = 0; g < ntags; ++g) acc += sp[g * 64];
      gin[tk][64 + d] = acc * tscale;
    }

    // ---- ph2: query = H * Wq^T; wave w owns q-tile w
    {
      const int q0 = w * 16;
      const float* ha = H + (size_t)(tok0 + l15) * DM + l4 * 8;
      const float* wq = Wq + (size_t)(q0 + l15) * DM + l4 * 8;
      f32x4 acc = {0.f, 0.f, 0.f, 0.f};
#pragma unroll 4
      for (int ks = 0; ks < 64; ++ks) {
        bf16x8 af = load_bf8(ha + ks * 32);
        bf16x8 bf = load_bf8(wq + ks * 32);
        acc = __builtin_amdgcn_mfma_f32_16x16x32_bf16(af, bf, acc, 0, 0, 0);
      }
#pragma unroll
      for (int i = 0; i < 4; ++i)
        gin[l4 * 4 + i][q0 + l15] = acc[i];
    }
    __syncthreads();

    // ---- ph3: gate = sigmoid(gin * Wg^T + bg); hub epilogue
    bf16x8 afr[4];
#pragma unroll
    for (int ks = 0; ks < 4; ++ks)
      afr[ks] = load_bf8(&gin[l15][ks * 32 + l4 * 8]);

    const float* wgb = Wg + (size_t)l15 * 128 + l4 * 8;
#pragma unroll
    for (int j = 0; j < 8; ++j) {
      const int ht = w * 8 + j;
      const float* wgp = wgb + (size_t)ht * 16 * 128;
      f32x4 acc = {0.f, 0.f, 0.f, 0.f};
#pragma unroll
      for (int ks = 0; ks < 4; ++ks) {
        bf16x8 bf = load_bf8(wgp + ks * 32);
        acc = __builtin_amdgcn_mfma_f32_16x16x32_bf16(afr[ks], bf, acc, 0, 0, 0);
      }
      const int h = ht * 16 + l15;
      const float bgv = bg[h];
#pragma unroll
      for (int i = 0; i < 4; ++i) {
        int tok = tok0 + l4 * 4 + i;
        float g = sigmoidf_(acc[i] + bgv);
        gate_out[(size_t)tok * DHS + h] = g;
        size_t so = (size_t)tok * DSZ + HUBOFF + h;
        outS[so] = S[so] * g + whs[(size_t)tok * DHS + h];
      }
    }
    asm volatile("" ::: "memory");   // block CSE across reps
  }
}

// ---------------------------------------------------------------------------
// K_fixup: out[region] = S[region] + w for spoke/hub_priv/tag (single).
// ---------------------------------------------------------------------------
__global__ __launch_bounds__(256) void cw_fixup_kernel(
    const float* __restrict__ S,
    const float* __restrict__ w_spoke, const float* __restrict__ w_hub_priv,
    const float* __restrict__ tg, const int* __restrict__ lip,
    float* __restrict__ outS)
{
  const int li = *lip;
  const unsigned sp0 = (unsigned)(li * 32);
  const unsigned hp0 = 768u + (unsigned)(li * 16);
  const unsigned tg0 = 1280u + (unsigned)(li * 16);

  const float4* S4 = reinterpret_cast<const float4*>(S);
  const float4* SP4 = reinterpret_cast<const float4*>(w_spoke);
  const float4* HP4 = reinterpret_cast<const float4*>(w_hub_priv);
  const float4* TG4 = reinterpret_cast<const float4*>(tg);
  float4* O4 = reinterpret_cast<float4*>(outS);

  unsigned t = blockIdx.x * 256u + threadIdx.x;   // 0..262143
  unsigned tok = t >> 4;
  unsigned j0 = (t & 15u) * 4u;
  unsigned col;
  const float4* src;
  if (j0 < 32u)      { col = sp0 + j0;         src = SP4 + (size_t)tok * 32u + j0; }
  else if (j0 < 48u) { col = hp0 + (j0 - 32u); src = HP4 + (size_t)tok * 16u + (j0 - 32u); }
  else               { col = tg0 + (j0 - 48u); src = TG4 + (size_t)tok * 16u + (j0 - 48u); }

  size_t idx = (size_t)tok * 1664u + col;
#pragma unroll
  for (int k = 0; k < 4; ++k) {
    float4 s = S4[idx + k];
    float4 v = src[k];
    s.x += v.x; s.y += v.y; s.z += v.z; s.w += v.w;
    O4[idx + k] = s;
  }
}

extern "C" void kernel_launch(void* const* d_in, const int* in_sizes, int n_in,
                              void* d_out, int out_size, void* d_ws, size_t ws_size,
                              hipStream_t stream) {
  (void)in_sizes; (void)n_in; (void)out_size; (void)d_ws; (void)ws_size;
  const float* S            = (const float*)d_in[0];
  const float* H            = (const float*)d_in[1];
  const float* w_spoke      = (const float*)d_in[2];
  const float* w_hub_priv   = (const float*)d_in[3];
  const float* w_hub_shared = (const float*)d_in[4];
  const float* tg           = (const float*)d_in[5];
  const float* Wq           = (const float*)d_in[6];
  const float* Wg           = (const float*)d_in[7];
  const float* bg           = (const float*)d_in[8];
  const int*   lip          = (const int*)d_in[9];

  float* outS = (float*)d_out;
  float* gate_out = outS + (size_t)NTOK * DSZ;

  cw_copy_kernel<<<4096, 256, 0, stream>>>(
      reinterpret_cast<const float4*>(S), reinterpret_cast<float4*>(outS));
  cw_gate_kernel<<<1024, 256, 0, stream>>>(S, H, Wq, Wg, bg, w_hub_shared,
                                           lip, outS, gate_out);
  cw_fixup_kernel<<<1024, 256, 0, stream>>>(S, w_spoke, w_hub_priv, tg, lip, outS);
}

// Round 11
// 347.614 us; speedup vs baseline: 3.6601x; 3.6601x over previous
//
#include <hip/hip_runtime.h>
#include <hip/hip_bf16.h>

// CognitiveWorkspace — 3 dispatches; this round replaces ONLY the gate kernel
// (v2: wave-K-split + deep load batching). Copy/fixup proven in R9/R10.
//   K_copy : flat float4 copy S -> outS              (~135 µs measured)
//   K_gate : gate GEMMs via bf16 MFMA; writes gate_out + hub region
//   K_fixup: spoke/hub_priv/tag overwrite            (~8 µs)

#define DM 2048      // d_model
#define DSZ 6656     // D_S
#define HUBOFF 4608  // hub_shared offset (floats)
#define TAGOFF 5120
#define NTOK 16384   // B*T
#define DHS 512      // d_hub_shared

typedef __attribute__((ext_vector_type(8))) short bf16x8;
typedef __attribute__((ext_vector_type(4))) float f32x4;

__device__ __forceinline__ float sigmoidf_(float x) {
  return 1.0f / (1.0f + __expf(-x));
}
__device__ __forceinline__ short f2bf(float x) {
  return (short)__bfloat16_as_ushort(__float2bfloat16(x));
}
__device__ __forceinline__ bf16x8 load_bf8(const float* p) {
  float4 a = *reinterpret_cast<const float4*>(p);
  float4 b = *reinterpret_cast<const float4*>(p + 4);
  bf16x8 r;
  r[0] = f2bf(a.x); r[1] = f2bf(a.y); r[2] = f2bf(a.z); r[3] = f2bf(a.w);
  r[4] = f2bf(b.x); r[5] = f2bf(b.y); r[6] = f2bf(b.z); r[7] = f2bf(b.w);
  return r;
}
#define MFMA(a, b, c) __builtin_amdgcn_mfma_f32_16x16x32_bf16((a), (b), (c), 0, 0, 0)

// ---------------------------------------------------------------------------
// K_copy: pure flat copy, 4096 blocks x 256 thr x 26 quads.
// ---------------------------------------------------------------------------
__global__ __launch_bounds__(256) void cw_copy_kernel(
    const float4* __restrict__ S4, float4* __restrict__ O4)
{
  size_t i = (size_t)blockIdx.x * 256 + threadIdx.x;
  const size_t stride = (size_t)4096 * 256;
#pragma unroll 2
  for (int k = 0; k < 26; ++k) {
    O4[i] = S4[i];
    i += stride;
  }
}

// ---------------------------------------------------------------------------
// K_gate v2: 1024 blocks, 16 tokens each, 256 threads (4 waves).
//  ph1: tag mean, float4-vectorized (8 loads in flight/thread)
//  ph2: query = H*Wq^T; K split across 4 waves (512 each); each wave does all
//       4 q-tiles; 10 x 32B loads in flight per 2-k-step batch; LDS-reduce.
//  ph3: gate = sigmoid(gin*Wg^T+bg), j-pair batched; hub epilogue.
// MFMA 16x16x32 bf16 (m89-verified): A row = lane&15 (token), k=(lane>>4)*8+e;
// C/D: col(lane&15)=N-idx, row=(lane>>4)*4+reg = token.
// ---------------------------------------------------------------------------
__global__ __launch_bounds__(256) void cw_gate_kernel(
    const float* __restrict__ S, const float* __restrict__ H,
    const float* __restrict__ Wq, const float* __restrict__ Wg,
    const float* __restrict__ bg, const float* __restrict__ whs,
    const int* __restrict__ lip,
    float* __restrict__ outS, float* __restrict__ gate_out)
{
  __shared__ float gin[16][132];       // 8448 B, stride 132
  __shared__ f32x4 part[4][4][64];     // 16 KB: [wave][qtile][lane]

  const int tid = threadIdx.x;
  const int li = *lip;
  const int start = (li > 8) ? (li - 8) : 0;
  const int ntags = li - start;
  const float tscale = (ntags > 0) ? (1.0f / (float)ntags) : 0.0f;
  const int trs = TAGOFF + start * 64;
  const int tok0 = blockIdx.x * 16;

  const int w = tid >> 6;
  const int l = tid & 63;
  const int l15 = l & 15, l4 = l >> 4;

  // ---- ph1: mean over past tags (vectorized). thread = (token tk, quad t16)
  {
    const int tk = tid >> 4, t16 = tid & 15;
    const float4* sp =
        reinterpret_cast<const float4*>(S + (size_t)(tok0 + tk) * DSZ + trs) + t16;
    float4 acc = {0.f, 0.f, 0.f, 0.f};
    for (int g = 0; g < ntags; ++g) {     // 8 independent float4 loads
      float4 v = sp[g * 16];
      acc.x += v.x; acc.y += v.y; acc.z += v.z; acc.w += v.w;
    }
    const int d = 64 + t16 * 4;
    gin[tk][d + 0] = acc.x * tscale;
    gin[tk][d + 1] = acc.y * tscale;
    gin[tk][d + 2] = acc.z * tscale;
    gin[tk][d + 3] = acc.w * tscale;
  }

  // ---- ph2: query; wave w covers K-chunk [w*512, w*512+512)
  {
    const size_t ko = (size_t)w * 512 + l4 * 8;
    const float* ha  = H + (size_t)(tok0 + l15) * DM + ko;
    const float* wq0 = Wq + (size_t)l15 * DM + ko;
    const float* wq1 = wq0 + (size_t)16 * DM;
    const float* wq2 = wq0 + (size_t)32 * DM;
    const float* wq3 = wq0 + (size_t)48 * DM;
    f32x4 acc0 = {0.f,0.f,0.f,0.f}, acc1 = {0.f,0.f,0.f,0.f};
    f32x4 acc2 = {0.f,0.f,0.f,0.f}, acc3 = {0.f,0.f,0.f,0.f};
    for (int it = 0; it < 8; ++it) {      // 2 k-steps per iter: 10 loads in flight
      const int off = it * 64;
      bf16x8 a0  = load_bf8(ha  + off);
      bf16x8 a1  = load_bf8(ha  + off + 32);
      bf16x8 b00 = load_bf8(wq0 + off);
      bf16x8 b01 = load_bf8(wq0 + off + 32);
      bf16x8 b10 = load_bf8(wq1 + off);
      bf16x8 b11 = load_bf8(wq1 + off + 32);
      bf16x8 b20 = load_bf8(wq2 + off);
      bf16x8 b21 = load_bf8(wq2 + off + 32);
      bf16x8 b30 = load_bf8(wq3 + off);
      bf16x8 b31 = load_bf8(wq3 + off + 32);
      acc0 = MFMA(a0, b00, acc0); acc0 = MFMA(a1, b01, acc0);
      acc1 = MFMA(a0, b10, acc1); acc1 = MFMA(a1, b11, acc1);
      acc2 = MFMA(a0, b20, acc2); acc2 = MFMA(a1, b21, acc2);
      acc3 = MFMA(a0, b30, acc3); acc3 = MFMA(a1, b31, acc3);
    }
    part[w][0][l] = acc0;
    part[w][1][l] = acc1;
    part[w][2][l] = acc2;
    part[w][3][l] = acc3;
  }
  __syncthreads();

  // ---- cross-wave K-reduction -> gin[tok][q]  (thread = (tile, lane))
  {
    const int tile = tid >> 6, lane = tid & 63;
    f32x4 s0 = part[0][tile][lane];
    f32x4 s1 = part[1][tile][lane];
    f32x4 s2 = part[2][tile][lane];
    f32x4 s3 = part[3][tile][lane];
    f32x4 sum;
    sum[0] = s0[0] + s1[0] + s2[0] + s3[0];
    sum[1] = s0[1] + s1[1] + s2[1] + s3[1];
    sum[2] = s0[2] + s1[2] + s2[2] + s3[2];
    sum[3] = s0[3] + s1[3] + s2[3] + s3[3];
    const int q = tile * 16 + (lane & 15);
    const int tb = (lane >> 4) * 4;
    gin[tb + 0][q] = sum[0];
    gin[tb + 1][q] = sum[1];
    gin[tb + 2][q] = sum[2];
    gin[tb + 3][q] = sum[3];
  }
  __syncthreads();

  // ---- ph3: gate = sigmoid(gin * Wg^T + bg); hub epilogue. j-pair batched.
  bf16x8 afr[4];
#pragma unroll
  for (int ks = 0; ks < 4; ++ks)
    afr[ks] = load_bf8(&gin[l15][ks * 32 + l4 * 8]);

  const float* wgb = Wg + (size_t)l15 * 128 + l4 * 8;
  for (int jp = 0; jp < 4; ++jp) {
    const int ht0 = w * 8 + jp * 2;          // h-tiles ht0, ht0+1
    const float* wp0 = wgb + (size_t)ht0 * 16 * 128;
    const float* wp1 = wp0 + (size_t)16 * 128;
    bf16x8 c00 = load_bf8(wp0);
    bf16x8 c01 = load_bf8(wp0 + 32);
    bf16x8 c02 = load_bf8(wp0 + 64);
    bf16x8 c03 = load_bf8(wp0 + 96);
    bf16x8 c10 = load_bf8(wp1);
    bf16x8 c11 = load_bf8(wp1 + 32);
    bf16x8 c12 = load_bf8(wp1 + 64);
    bf16x8 c13 = load_bf8(wp1 + 96);
    f32x4 accA = {0.f,0.f,0.f,0.f}, accB = {0.f,0.f,0.f,0.f};
    accA = MFMA(afr[0], c00, accA); accA = MFMA(afr[1], c01, accA);
    accA = MFMA(afr[2], c02, accA); accA = MFMA(afr[3], c03, accA);
    accB = MFMA(afr[0], c10, accB); accB = MFMA(afr[1], c11, accB);
    accB = MFMA(afr[2], c12, accB); accB = MFMA(afr[3], c13, accB);
#pragma unroll
    for (int t = 0; t < 2; ++t) {
      const f32x4 a = t ? accB : accA;
      const int h = (ht0 + t) * 16 + l15;
      const float bgv = bg[h];
#pragma unroll
      for (int i = 0; i < 4; ++i) {
        const int tok = tok0 + l4 * 4 + i;
        const float g = sigmoidf_(a[i] + bgv);
        gate_out[(size_t)tok * DHS + h] = g;
        const size_t so = (size_t)tok * DSZ + HUBOFF + h;
        outS[so] = S[so] * g + whs[(size_t)tok * DHS + h];
      }
    }
  }
}

// ---------------------------------------------------------------------------
// K_fixup: out[region] = S[region] + w for spoke/hub_priv/tag.
// ---------------------------------------------------------------------------
__global__ __launch_bounds__(256) void cw_fixup_kernel(
    const float* __restrict__ S,
    const float* __restrict__ w_spoke, const float* __restrict__ w_hub_priv,
    const float* __restrict__ tg, const int* __restrict__ lip,
    float* __restrict__ outS)
{
  const int li = *lip;
  const unsigned sp0 = (unsigned)(li * 32);
  const unsigned hp0 = 768u + (unsigned)(li * 16);
  const unsigned tg0 = 1280u + (unsigned)(li * 16);

  const float4* S4 = reinterpret_cast<const float4*>(S);
  const float4* SP4 = reinterpret_cast<const float4*>(w_spoke);
  const float4* HP4 = reinterpret_cast<const float4*>(w_hub_priv);
  const float4* TG4 = reinterpret_cast<const float4*>(tg);
  float4* O4 = reinterpret_cast<float4*>(outS);

  unsigned t = blockIdx.x * 256u + threadIdx.x;   // 0..262143
  unsigned tok = t >> 4;
  unsigned j0 = (t & 15u) * 4u;
  unsigned col;
  const float4* src;
  if (j0 < 32u)      { col = sp0 + j0;         src = SP4 + (size_t)tok * 32u + j0; }
  else if (j0 < 48u) { col = hp0 + (j0 - 32u); src = HP4 + (size_t)tok * 16u + (j0 - 32u); }
  else               { col = tg0 + (j0 - 48u); src = TG4 + (size_t)tok * 16u + (j0 - 48u); }

  size_t idx = (size_t)tok * 1664u + col;
#pragma unroll
  for (int k = 0; k < 4; ++k) {
    float4 s = S4[idx + k];
    float4 v = src[k];
    s.x += v.x; s.y += v.y; s.z += v.z; s.w += v.w;
    O4[idx + k] = s;
  }
}

extern "C" void kernel_launch(void* const* d_in, const int* in_sizes, int n_in,
                              void* d_out, int out_size, void* d_ws, size_t ws_size,
                              hipStream_t stream) {
  (void)in_sizes; (void)n_in; (void)out_size; (void)d_ws; (void)ws_size;
  const float* S            = (const float*)d_in[0];
  const float* H            = (const float*)d_in[1];
  const float* w_spoke      = (const float*)d_in[2];
  const float* w_hub_priv   = (const float*)d_in[3];
  const float* w_hub_shared = (const float*)d_in[4];
  const float* tg           = (const float*)d_in[5];
  const float* Wq           = (const float*)d_in[6];
  const float* Wg           = (const float*)d_in[7];
  const float* bg           = (const float*)d_in[8];
  const int*   lip          = (const int*)d_in[9];

  float* outS = (float*)d_out;
  float* gate_out = outS + (size_t)NTOK * DSZ;

  cw_copy_kernel<<<4096, 256, 0, stream>>>(
      reinterpret_cast<const float4*>(S), reinterpret_cast<float4*>(outS));
  cw_gate_kernel<<<1024, 256, 0, stream>>>(S, H, Wq, Wg, bg, w_hub_shared,
                                           lip, outS, gate_out);
  cw_fixup_kernel<<<1024, 256, 0, stream>>>(S, w_spoke, w_hub_priv, tg, lip, outS);
}

// Round 12
// 334.434 us; speedup vs baseline: 3.8043x; 1.0394x over previous
//
#include <hip/hip_runtime.h>
#include <hip/hip_bf16.h>

// CognitiveWorkspace — 4 dispatches.
//   K_copy : flat float4 copy S -> outS (135 µs measured, R10)
//   K_qpart: query partials, K split across blocks (8192 blocks), raw-loads-
//            first MFMA; partials -> gate region of d_out
//   K_gfin : tag-mean + partial-sum -> gin; Wg MFMA; coalesced hub+gate epilogue
//   K_fixup: spoke/hub_priv/tag overwrite (~8 µs)

#define DM 2048      // d_model
#define DSZ 6656     // D_S
#define HUBOFF 4608  // hub_shared offset (floats)
#define TAGOFF 5120
#define NTOK 16384   // B*T
#define DHS 512      // d_hub_shared

typedef __attribute__((ext_vector_type(8))) short bf16x8;
typedef __attribute__((ext_vector_type(4))) float f32x4;

__device__ __forceinline__ float sigmoidf_(float x) {
  return 1.0f / (1.0f + __expf(-x));
}
__device__ __forceinline__ short f2bf(float x) {
  return (short)__bfloat16_as_ushort(__float2bfloat16(x));
}
__device__ __forceinline__ bf16x8 cvt8(float4 a, float4 b) {
  bf16x8 r;
  r[0] = f2bf(a.x); r[1] = f2bf(a.y); r[2] = f2bf(a.z); r[3] = f2bf(a.w);
  r[4] = f2bf(b.x); r[5] = f2bf(b.y); r[6] = f2bf(b.z); r[7] = f2bf(b.w);
  return r;
}
#define MFMA(a, b, c) __builtin_amdgcn_mfma_f32_16x16x32_bf16((a), (b), (c), 0, 0, 0)

// ---------------------------------------------------------------------------
// K_copy: pure flat copy, 4096 blocks x 256 thr x 26 quads.
// ---------------------------------------------------------------------------
__global__ __launch_bounds__(256) void cw_copy_kernel(
    const float4* __restrict__ S4, float4* __restrict__ O4)
{
  size_t i = (size_t)blockIdx.x * 256 + threadIdx.x;
  const size_t stride = (size_t)4096 * 256;
#pragma unroll 2
  for (int k = 0; k < 26; ++k) {
    O4[i] = S4[i];
    i += stride;
  }
}

// ---------------------------------------------------------------------------
// K_qpart: 8192 blocks: tt = bid>>3 (16-token tile), kc = bid&7 (K chunk 256).
// Wave w owns ksteps {2w, 2w+1} (k = kc*256 + w*64 + {0,32}); computes all
// 4 q-tiles; LDS cross-wave reduce; partial -> gate region [tok][kc*64+q].
// MFMA 16x16x32 bf16 (m89): A row = lane&15, k=(lane>>4)*8+e;
// C/D: col = lane&15 (q), row = (lane>>4)*4+reg (token).
// ---------------------------------------------------------------------------
__global__ __launch_bounds__(256) void cw_qpart_kernel(
    const float* __restrict__ H, const float* __restrict__ Wq,
    float* __restrict__ qpart)
{
  __shared__ f32x4 part[4][4][64];   // 16 KB [wave][qtile][lane]
  const int tid = threadIdx.x;
  const int w = tid >> 6, l = tid & 63, l15 = l & 15, l4 = l >> 4;
  const int tt = blockIdx.x >> 3, kc = blockIdx.x & 7;
  const int tok0 = tt * 16;
  const int kb = kc * 256 + w * 64 + l4 * 8;
  const float* ha = H + (size_t)(tok0 + l15) * DM + kb;
  const float* wq = Wq + (size_t)l15 * DM + kb;

  // ---- issue ALL 20 raw float4 loads before any conversion/MFMA
  float4 ra[2][2], rb[4][2][2];
#pragma unroll
  for (int s = 0; s < 2; ++s) {
    ra[s][0] = *reinterpret_cast<const float4*>(ha + s * 32);
    ra[s][1] = *reinterpret_cast<const float4*>(ha + s * 32 + 4);
  }
#pragma unroll
  for (int q = 0; q < 4; ++q)
#pragma unroll
    for (int s = 0; s < 2; ++s) {
      const float* p = wq + (size_t)q * 16 * DM + s * 32;
      rb[q][s][0] = *reinterpret_cast<const float4*>(p);
      rb[q][s][1] = *reinterpret_cast<const float4*>(p + 4);
    }

  bf16x8 af0 = cvt8(ra[0][0], ra[0][1]);
  bf16x8 af1 = cvt8(ra[1][0], ra[1][1]);
  f32x4 acc[4] = {{0,0,0,0},{0,0,0,0},{0,0,0,0},{0,0,0,0}};
#pragma unroll
  for (int q = 0; q < 4; ++q) {
    acc[q] = MFMA(af0, cvt8(rb[q][0][0], rb[q][0][1]), acc[q]);
    acc[q] = MFMA(af1, cvt8(rb[q][1][0], rb[q][1][1]), acc[q]);
  }
#pragma unroll
  for (int q = 0; q < 4; ++q) part[w][q][l] = acc[q];
  __syncthreads();

  // cross-wave reduce; thread = (qtile = tid>>6, lane)
  {
    const int qt = tid >> 6, ln = tid & 63;
    f32x4 s0 = part[0][qt][ln], s1 = part[1][qt][ln];
    f32x4 s2 = part[2][qt][ln], s3 = part[3][qt][ln];
    const int row = (ln >> 4) * 4, q = qt * 16 + (ln & 15);
#pragma unroll
    for (int i = 0; i < 4; ++i)
      qpart[(size_t)(tok0 + row + i) * DHS + kc * 64 + q] =
          s0[i] + s1[i] + s2[i] + s3[i];
  }
}

// ---------------------------------------------------------------------------
// K_gfin: 1024 blocks x 16 tokens. tag-mean + partial-sum -> gin;
// gate = sigmoid(gin*Wg^T+bg) (MFMA, raw-loads-first); coalesced epilogue:
// gate_out (overwrites partials) and outS hub = S*g + whs, all float4.
// ---------------------------------------------------------------------------
__global__ __launch_bounds__(256) void cw_gfin_kernel(
    const float* __restrict__ S, const float* __restrict__ Wg,
    const float* __restrict__ bg, const float* __restrict__ whs,
    const int* __restrict__ lip,
    float* __restrict__ outS, float* __restrict__ gate_out)
{
  __shared__ float gin[16][132];     // 8.4 KB
  __shared__ float gtile[16][516];   // 33 KB

  const int tid = threadIdx.x;
  const int li = *lip;
  const int start = (li > 8) ? (li - 8) : 0;
  const int ntags = li - start;
  const float tscale = (ntags > 0) ? (1.0f / (float)ntags) : 0.0f;
  const int trs = TAGOFF + start * 64;
  const int tok0 = blockIdx.x * 16;
  const int w = tid >> 6, l = tid & 63, l15 = l & 15, l4 = l >> 4;

  // ---- tag mean (vectorized)
  {
    const int tk = tid >> 4, t16 = tid & 15;
    const float4* sp =
        reinterpret_cast<const float4*>(S + (size_t)(tok0 + tk) * DSZ + trs) + t16;
    float4 acc = {0.f, 0.f, 0.f, 0.f};
    for (int g = 0; g < ntags; ++g) {
      float4 v = sp[g * 16];
      acc.x += v.x; acc.y += v.y; acc.z += v.z; acc.w += v.w;
    }
    const int d = 64 + t16 * 4;
    gin[tk][d + 0] = acc.x * tscale;
    gin[tk][d + 1] = acc.y * tscale;
    gin[tk][d + 2] = acc.z * tscale;
    gin[tk][d + 3] = acc.w * tscale;
  }
  // ---- sum 8 K-chunk partials -> gin[row][0..63]
  {
    const int row = tid >> 4, q4 = tid & 15;
    const float* pp = gate_out + (size_t)(tok0 + row) * DHS + q4 * 4;
    float4 a = {0.f, 0.f, 0.f, 0.f};
#pragma unroll
    for (int kc = 0; kc < 8; ++kc) {
      float4 v = *reinterpret_cast<const float4*>(pp + kc * 64);
      a.x += v.x; a.y += v.y; a.z += v.z; a.w += v.w;
    }
    gin[row][q4 * 4 + 0] = a.x;
    gin[row][q4 * 4 + 1] = a.y;
    gin[row][q4 * 4 + 2] = a.z;
    gin[row][q4 * 4 + 3] = a.w;
  }
  __syncthreads();

  // ---- Wg MFMA (j-pair batched, raw loads first)
  bf16x8 afr[4];
#pragma unroll
  for (int ks = 0; ks < 4; ++ks) {
    const float* p = &gin[l15][ks * 32 + l4 * 8];
    afr[ks] = cvt8(*reinterpret_cast<const float4*>(p),
                   *reinterpret_cast<const float4*>(p + 4));
  }
  const float* wgb = Wg + (size_t)l15 * 128 + l4 * 8;
  for (int jp = 0; jp < 4; ++jp) {
    const int ht0 = w * 8 + jp * 2;
    const float* wp0 = wgb + (size_t)ht0 * 16 * 128;
    const float* wp1 = wp0 + 16 * 128;
    float4 r0[4][2], r1[4][2];
#pragma unroll
    for (int ks = 0; ks < 4; ++ks) {
      r0[ks][0] = *reinterpret_cast<const float4*>(wp0 + ks * 32);
      r0[ks][1] = *reinterpret_cast<const float4*>(wp0 + ks * 32 + 4);
      r1[ks][0] = *reinterpret_cast<const float4*>(wp1 + ks * 32);
      r1[ks][1] = *reinterpret_cast<const float4*>(wp1 + ks * 32 + 4);
    }
    f32x4 accA = {0,0,0,0}, accB = {0,0,0,0};
#pragma unroll
    for (int ks = 0; ks < 4; ++ks) {
      accA = MFMA(afr[ks], cvt8(r0[ks][0], r0[ks][1]), accA);
      accB = MFMA(afr[ks], cvt8(r1[ks][0], r1[ks][1]), accB);
    }
#pragma unroll
    for (int t = 0; t < 2; ++t) {
      const f32x4 a = t ? accB : accA;
      const int h = (ht0 + t) * 16 + l15;
      const float bgv = bg[h];
#pragma unroll
      for (int i = 0; i < 4; ++i)
        gtile[l4 * 4 + i][h] = sigmoidf_(a[i] + bgv);
    }
  }
  __syncthreads();

  // ---- coalesced epilogue: 16 rows x 128 quads
#pragma unroll
  for (int r2 = 0; r2 < 8; ++r2) {
    const int idx = r2 * 256 + tid;
    const int row = idx >> 7, qq = idx & 127;
    const int tok = tok0 + row;
    float4 g = *reinterpret_cast<const float4*>(&gtile[row][qq * 4]);
    float4 s = *reinterpret_cast<const float4*>(S + (size_t)tok * DSZ + HUBOFF + qq * 4);
    float4 wv = *reinterpret_cast<const float4*>(whs + (size_t)tok * DHS + qq * 4);
    float4 o;
    o.x = s.x * g.x + wv.x;
    o.y = s.y * g.y + wv.y;
    o.z = s.z * g.z + wv.z;
    o.w = s.w * g.w + wv.w;
    *reinterpret_cast<float4*>(outS + (size_t)tok * DSZ + HUBOFF + qq * 4) = o;
    *reinterpret_cast<float4*>(gate_out + (size_t)tok * DHS + qq * 4) = g;
  }
}

// ---------------------------------------------------------------------------
// K_fixup: out[region] = S[region] + w for spoke/hub_priv/tag.
// ---------------------------------------------------------------------------
__global__ __launch_bounds__(256) void cw_fixup_kernel(
    const float* __restrict__ S,
    const float* __restrict__ w_spoke, const float* __restrict__ w_hub_priv,
    const float* __restrict__ tg, const int* __restrict__ lip,
    float* __restrict__ outS)
{
  const int li = *lip;
  const unsigned sp0 = (unsigned)(li * 32);
  const unsigned hp0 = 768u + (unsigned)(li * 16);
  const unsigned tg0 = 1280u + (unsigned)(li * 16);

  const float4* S4 = reinterpret_cast<const float4*>(S);
  const float4* SP4 = reinterpret_cast<const float4*>(w_spoke);
  const float4* HP4 = reinterpret_cast<const float4*>(w_hub_priv);
  const float4* TG4 = reinterpret_cast<const float4*>(tg);
  float4* O4 = reinterpret_cast<float4*>(outS);

  unsigned t = blockIdx.x * 256u + threadIdx.x;   // 0..262143
  unsigned tok = t >> 4;
  unsigned j0 = (t & 15u) * 4u;
  unsigned col;
  const float4* src;
  if (j0 < 32u)      { col = sp0 + j0;         src = SP4 + (size_t)tok * 32u + j0; }
  else if (j0 < 48u) { col = hp0 + (j0 - 32u); src = HP4 + (size_t)tok * 16u + (j0 - 32u); }
  else               { col = tg0 + (j0 - 48u); src = TG4 + (size_t)tok * 16u + (j0 - 48u); }

  size_t idx = (size_t)tok * 1664u + col;
#pragma unroll
  for (int k = 0; k < 4; ++k) {
    float4 s = S4[idx + k];
    float4 v = src[k];
    s.x += v.x; s.y += v.y; s.z += v.z; s.w += v.w;
    O4[idx + k] = s;
  }
}

extern "C" void kernel_launch(void* const* d_in, const int* in_sizes, int n_in,
                              void* d_out, int out_size, void* d_ws, size_t ws_size,
                              hipStream_t stream) {
  (void)in_sizes; (void)n_in; (void)out_size; (void)d_ws; (void)ws_size;
  const float* S            = (const float*)d_in[0];
  const float* H            = (const float*)d_in[1];
  const float* w_spoke      = (const float*)d_in[2];
  const float* w_hub_priv   = (const float*)d_in[3];
  const float* w_hub_shared = (const float*)d_in[4];
  const float* tg           = (const float*)d_in[5];
  const float* Wq           = (const float*)d_in[6];
  const float* Wg           = (const float*)d_in[7];
  const float* bg           = (const float*)d_in[8];
  const int*   lip          = (const int*)d_in[9];

  float* outS = (float*)d_out;
  float* gate_out = outS + (size_t)NTOK * DSZ;

  cw_copy_kernel<<<4096, 256, 0, stream>>>(
      reinterpret_cast<const float4*>(S), reinterpret_cast<float4*>(outS));
  cw_qpart_kernel<<<8192, 256, 0, stream>>>(H, Wq, gate_out);
  cw_gfin_kernel<<<1024, 256, 0, stream>>>(S, Wg, bg, w_hub_shared, lip,
                                           outS, gate_out);
  cw_fixup_kernel<<<1024, 256, 0, stream>>>(S, w_spoke, w_hub_priv, tg, lip, outS);
}